// Round 5
// baseline (144.657 us; speedup 1.0000x reference)
//
#include <hip/hip_runtime.h>
#include <math.h>

#define E_    256
#define H_    512
#define F_    100
#define MCL_  500
#define CTX_  499
#define V_    128000
#define EPS_  1e-8f

typedef float f4v __attribute__((ext_vector_type(4)));

// workspace layout (float offsets)
#define WS_FE      0                      // 500*256 (row 499 = mean fact)
#define WS_ENERGY  (WS_FE + MCL_*E_)      // 500
#define WS_EBIAS   (WS_ENERGY + MCL_)     // 500
#define WS_AW      (WS_EBIAS + MCL_)      // 512 (500 used)
#define WS_MEANP   (WS_AW + 512)          // 8*256 mean partials
#define WS_AWFP    (WS_MEANP + 8*E_)      // 8*256 awf partials
#define WS_FMAX    (WS_AWFP + 8*E_)       // 256
#define WS_HNEW    (WS_FMAX + E_)         // 512
#define WS_ACT     (WS_HNEW + H_)         // 512
#define WS_LOGITS  (WS_ACT + H_)          // 128000
#define WS_BSUM    (WS_LOGITS + V_)       // 1024
#define WS_CNT     (WS_BSUM + 1024)       // 3 ints: fact-done, mean-sub, energy

__device__ __forceinline__ float wred64(float v) {
#pragma unroll
  for (int o = 32; o; o >>= 1) v += __shfl_xor(v, o, 64);
  return v;
}
__device__ __forceinline__ float qred16(float v) {
#pragma unroll
  for (int o = 8; o; o >>= 1) v += __shfl_xor(v, o, 64);
  return v;
}
__device__ __forceinline__ float dot4(float4 a, float4 b) {
  return a.x*b.x + a.y*b.y + a.z*b.z + a.w*b.w;
}
__device__ __forceinline__ float dot4v(f4v a, f4v b) {
  return a.x*b.x + a.y*b.y + a.z*b.z + a.w*b.w;
}

// K1: blocks 0-249 facts (2 rows, float2); 250-257 ebias; 258-265 mean (spin on facts)
__global__ __launch_bounds__(256) void k_encode(const int* __restrict__ ctx,
                                                const float* __restrict__ wemb,
                                                float* __restrict__ fe,
                                                const float* __restrict__ a1W,
                                                const float* __restrict__ a1b,
                                                const float* __restrict__ h0,
                                                float* __restrict__ ebias,
                                                const int* __restrict__ nfp,
                                                float* __restrict__ meanp,
                                                int* __restrict__ cnt) {
  const int t = threadIdx.x;
  const int b = blockIdx.x;

  if (b >= 258) {  // ---- mean blocks ----
    const int m = b - 258;
    const int nf = *nfp;
    const int chunk = (nf + 7) >> 3;
    const int lo = m * chunk;
    const int hi = min(nf, lo + chunk);
    if (t == 0) {
      while (atomicAdd(cnt, 0) < 250) __builtin_amdgcn_s_sleep(8);
    }
    __syncthreads();
    __threadfence();
    float s0 = 0.f, s1 = 0.f, s2 = 0.f, s3 = 0.f;
    int i = lo;
    for (; i + 4 <= hi; i += 4) {
      s0 += fe[(i + 0) * E_ + t]; s1 += fe[(i + 1) * E_ + t];
      s2 += fe[(i + 2) * E_ + t]; s3 += fe[(i + 3) * E_ + t];
    }
    for (; i < hi; ++i) s0 += fe[i * E_ + t];
    meanp[m * E_ + t] = (s0 + s1) + (s2 + s3);
    __syncthreads();
    __threadfence();
    __shared__ int tick;
    if (t == 0) tick = atomicAdd(cnt + 1, 1);
    __syncthreads();
    if (tick != 7) return;
    __threadfence();
    float s = 0.f;
#pragma unroll
    for (int q = 0; q < 8; ++q) s += meanp[q * E_ + t];
    fe[CTX_ * E_ + t] = s / (float)nf;
    return;
  }

  if (b >= 250) {  // ---- ebias: ebias[j] = a1b[j] + h0 . a1W[j,256:768] ----
    const int lane = t & 63, sub = lane & 15, grp = lane >> 4;
    const int wid = (b - 250) * 4 + (t >> 6);
    const float4* h4 = (const float4*)h0;
    float4 hr[8];
#pragma unroll
    for (int q = 0; q < 8; ++q) hr[q] = h4[sub + q * 16];
    for (int j0 = wid * 4; j0 < MCL_; j0 += 32 * 4) {
      const int j = j0 + grp;
      if (j < MCL_) {
        const float4* w4 = (const float4*)(a1W + (size_t)j * (E_ + H_) + E_);
        float acc = 0.f;
#pragma unroll
        for (int q = 0; q < 8; ++q) acc += dot4(w4[sub + q * 16], hr[q]);
        acc = qred16(acc);
        if (sub == 0) ebias[j] = acc + a1b[j];
      }
    }
    return;
  }

  // ---- fact blocks ----
  __shared__ int toks[2][F_];
  if (t < F_) toks[0][t] = ctx[(b * 2) * F_ + t];
  else if (t < 2 * F_) toks[1][t - F_] = (b * 2 + 1 < CTX_) ? ctx[(b * 2 + 1) * F_ + (t - F_)] : 0;
  __syncthreads();
  const int row = t >> 7, tt = t & 127;
  const int i = b * 2 + row;
  const float e0n = (2 * tt) * (1.0f / 255.0f);
  const float e1n = (2 * tt + 1) * (1.0f / 255.0f);
  float x0 = 0.f, y0 = 0.f, x1 = 0.f, y1 = 0.f, x2 = 0.f, y2 = 0.f, x3 = 0.f, y3 = 0.f;
#pragma unroll 5
  for (int f = 0; f < F_; f += 4) {
#pragma unroll
    for (int u = 0; u < 4; ++u) {
      float s = (f + u) * (1.0f / 99.0f);
      float A = 1.0f - s, B = 1.0f - 2.0f * s;
      float2 v = ((const float2*)(wemb + (size_t)toks[row][f + u] * E_))[tt];
      if (u == 0)      { x0 = fmaf(v.x, A - e0n * B, x0); y0 = fmaf(v.y, A - e1n * B, y0); }
      else if (u == 1) { x1 = fmaf(v.x, A - e0n * B, x1); y1 = fmaf(v.y, A - e1n * B, y1); }
      else if (u == 2) { x2 = fmaf(v.x, A - e0n * B, x2); y2 = fmaf(v.y, A - e1n * B, y2); }
      else             { x3 = fmaf(v.x, A - e0n * B, x3); y3 = fmaf(v.y, A - e1n * B, y3); }
    }
  }
  if (i < CTX_) {
    float2 r; r.x = (x0 + x1) + (x2 + x3); r.y = (y0 + y1) + (y2 + y3);
    ((float2*)(fe + (size_t)i * E_))[tt] = r;
  }
  __syncthreads();
  __threadfence();
  if (t == 0) atomicAdd(cnt, 1);
}

// K2: energy GEMV (125 uniform blocks); last-ticket block: softmax+log_aw+argmax+fmaxrow
__global__ __launch_bounds__(256) void k_energy(const float* __restrict__ fe,
                                                const float* __restrict__ a1W,
                                                const float* __restrict__ ebias,
                                                const float* __restrict__ a2W,
                                                const float* __restrict__ a2b,
                                                const int* __restrict__ nfp,
                                                float* __restrict__ energy,
                                                float* __restrict__ aw_ws,
                                                float* __restrict__ fmaxrow,
                                                float* __restrict__ out_logaw,
                                                int* __restrict__ cnt) {
  __shared__ float sfe[4][E_];
  __shared__ float sred[4][256];
  __shared__ int sticket;
  const int t = threadIdx.x;
  const int i0 = blockIdx.x * 4;
  const int nf = *nfp;

#pragma unroll
  for (int r = 0; r < 4; ++r) sfe[r][t] = fe[(i0 + r) * E_ + t];
  __syncthreads();
  float c0 = 0.f, c1 = 0.f, c2 = 0.f, c3 = 0.f;
  const float4* s0p = (const float4*)sfe[0];
  const float4* s1p = (const float4*)sfe[1];
  const float4* s2p = (const float4*)sfe[2];
  const float4* s3p = (const float4*)sfe[3];
  for (int j = t; j < MCL_; j += 256) {
    const float4* w4 = (const float4*)(a1W + (size_t)j * (E_ + H_));
    float d0 = 0.f, d1 = 0.f, d2 = 0.f, d3 = 0.f;
#pragma unroll 8
    for (int q = 0; q < E_ / 4; ++q) {
      float4 a = w4[q];
      d0 += dot4(a, s0p[q]);
      d1 += dot4(a, s1p[q]);
      d2 += dot4(a, s2p[q]);
      d3 += dot4(a, s3p[q]);
    }
    float bj = ebias[j], wj = a2W[j];
    c0 = fmaf(wj, tanhf(d0 + bj), c0);
    c1 = fmaf(wj, tanhf(d1 + bj), c1);
    c2 = fmaf(wj, tanhf(d2 + bj), c2);
    c3 = fmaf(wj, tanhf(d3 + bj), c3);
  }
  sred[0][t] = c0; sred[1][t] = c1; sred[2][t] = c2; sred[3][t] = c3;
  __syncthreads();
  for (int s = 128; s; s >>= 1) {
    if (t < s) {
#pragma unroll
      for (int r = 0; r < 4; ++r) sred[r][t] += sred[r][t + s];
    }
    __syncthreads();
  }
  if (t < 4) energy[i0 + t] = sred[t][0] + a2b[0];

  __syncthreads();
  __threadfence();
  if (t == 0) sticket = atomicAdd(cnt + 2, 1);
  __syncthreads();
  if (sticket != 124) return;
  __threadfence();

  // ---- softmax tail (cheap: 500 elems + 1KB fmaxrow copy) ----
  float* red = sred[0];
  int* idx = (int*)sred[1];
  float ev0 = energy[t];
  float ev1 = (t + 256 < MCL_) ? energy[t + 256] : -1e30f;
  red[t] = fmaxf(ev0, ev1); __syncthreads();
  for (int s = 128; s; s >>= 1) { if (t < s) red[t] = fmaxf(red[t], red[t + s]); __syncthreads(); }
  const float mx = red[0]; __syncthreads();

  float p0 = __expf(ev0 - mx);
  float p1 = (t + 256 < MCL_) ? __expf(ev1 - mx) : 0.f;
  red[t] = p0 + p1; __syncthreads();
  for (int s = 128; s; s >>= 1) { if (t < s) red[t] += red[t + s]; __syncthreads(); }
  const float S1 = red[0]; __syncthreads();

  float m0 = ((t < nf) || (t == MCL_ - 1)) ? 1.f : 0.f;
  float m1 = (((t + 256) < nf) || ((t + 256) == MCL_ - 1)) ? 1.f : 0.f;
  float a0 = p0 / S1 * m0 + EPS_;
  float a1 = (t + 256 < MCL_) ? (p1 / S1 * m1 + EPS_) : 0.f;
  red[t] = a0 + a1; __syncthreads();
  for (int s = 128; s; s >>= 1) { if (t < s) red[t] += red[t + s]; __syncthreads(); }
  const float S2 = red[0]; __syncthreads();

  a0 /= S2; a1 /= S2;
  out_logaw[t] = logf(a0);
  aw_ws[t] = a0;
  if (t + 256 < MCL_) { out_logaw[t + 256] = logf(a1); aw_ws[t + 256] = a1; }

  float bv; int bi;
  if ((t + 256 < MCL_) && (a1 > a0)) { bv = a1; bi = t + 256; } else { bv = a0; bi = t; }
  red[t] = bv; idx[t] = bi; __syncthreads();
  for (int s = 128; s; s >>= 1) {
    if (t < s) {
      float o = red[t + s]; int oi = idx[t + s];
      if (o > red[t] || (o == red[t] && oi < idx[t])) { red[t] = o; idx[t] = oi; }
    }
    __syncthreads();
  }
  const int fidx = idx[0]; __syncthreads();
  fmaxrow[t] = fe[fidx * E_ + t];
}

// K3: blocks 0-127 gates+GRU (one h per wave); blocks 128-135 awf partials
__global__ __launch_bounds__(256) void k_gates_gru(const float* __restrict__ Wih,
                                                   const float* __restrict__ bih,
                                                   const float* __restrict__ Whh,
                                                   const float* __restrict__ bhh,
                                                   const float* __restrict__ wemb,
                                                   const float* __restrict__ fmaxrow,
                                                   const float* __restrict__ h0,
                                                   const float* __restrict__ aw,
                                                   const float* __restrict__ fe,
                                                   float* __restrict__ awfp,
                                                   float* __restrict__ hnew,
                                                   float* __restrict__ out_hidden) {
  const int t = threadIdx.x;
  const int b = blockIdx.x;
  if (b >= 128) {  // ---- awf partials: awfp[m][e] = sum_{i in chunk} aw[i]*fe[i,e] ----
    const int m = b - 128;
    const int lo = m * 63;
    const int hi = min(MCL_, lo + 63);
    float pa = 0.f, pb = 0.f;
    int i = lo;
    for (; i + 2 <= hi; i += 2) {
      pa = fmaf(aw[i], fe[i * E_ + t], pa);
      pb = fmaf(aw[i + 1], fe[(i + 1) * E_ + t], pb);
    }
    if (i < hi) pa = fmaf(aw[i], fe[i * E_ + t], pa);
    awfp[m * E_ + t] = pa + pb;
    return;
  }
  const int lane = t & 63, w = t >> 6;
  const int h = b * 4 + w;
  const float4* xa4 = (const float4*)(wemb + E_);  // word_emb row 1
  const float4* xb4 = (const float4*)fmaxrow;
  const float4* h4  = (const float4*)h0;
  float4 xav = xa4[lane], xbv = xb4[lane];
  float4 hva = h4[lane], hvb = h4[lane + 64];
  const float* rr = Wih + (size_t)h * (2 * E_ + F_);
  const float* rz = Wih + (size_t)(H_ + h) * (2 * E_ + F_);
  const float* rn = Wih + (size_t)(2 * H_ + h) * (2 * E_ + F_);
  float gir = dot4(((const float4*)rr)[lane], xav) + dot4(((const float4*)(rr + E_ + F_))[lane], xbv);
  float giz = dot4(((const float4*)rz)[lane], xav) + dot4(((const float4*)(rz + E_ + F_))[lane], xbv);
  float gin = dot4(((const float4*)rn)[lane], xav) + dot4(((const float4*)(rn + E_ + F_))[lane], xbv);
  const float4* wr = (const float4*)(Whh + (size_t)h * H_);
  const float4* wz = (const float4*)(Whh + (size_t)(H_ + h) * H_);
  const float4* wn = (const float4*)(Whh + (size_t)(2 * H_ + h) * H_);
  float ghr = dot4(wr[lane], hva) + dot4(wr[lane + 64], hvb);
  float ghz = dot4(wz[lane], hva) + dot4(wz[lane + 64], hvb);
  float ghn = dot4(wn[lane], hva) + dot4(wn[lane + 64], hvb);
  gir = wred64(gir); giz = wred64(giz); gin = wred64(gin);
  ghr = wred64(ghr); ghz = wred64(ghz); ghn = wred64(ghn);
  if (lane == 0) {
    float r = 1.f / (1.f + __expf(-(gir + bih[h] + ghr + bhh[h])));
    float z = 1.f / (1.f + __expf(-(giz + bih[H_ + h] + ghz + bhh[H_ + h])));
    float n = tanhf(gin + bih[2 * H_ + h] + r * (ghn + bhh[2 * H_ + h]));
    float hv = (1.f - z) * n + z * h0[h];
    hnew[h] = hv;
    out_hidden[h] = hv;
  }
}

// K4: act = relu([h_new | sum(awfp)] . out1_W^T + out1_b)
__global__ __launch_bounds__(256) void k_out1(const float* __restrict__ o1W,
                                              const float* __restrict__ o1b,
                                              const float* __restrict__ hnew,
                                              const float* __restrict__ awfp,
                                              float* __restrict__ act) {
  __shared__ float cat[H_ + E_];
  const int t = threadIdx.x;
#pragma unroll
  for (int idx = t; idx < H_; idx += 256) cat[idx] = hnew[idx];
  {
    float s = 0.f;
#pragma unroll
    for (int q = 0; q < 8; ++q) s += awfp[q * E_ + t];
    cat[H_ + t] = s;
  }
  __syncthreads();
  const int lane = t & 63, sub = lane & 15, grp = lane >> 4;
  const int gw = blockIdx.x * 4 + (t >> 6);
  const float4* c4 = (const float4*)cat;
  const int r = gw * 4 + grp;
  const float4* w4 = (const float4*)(o1W + (size_t)r * (H_ + E_));
  float acc = 0.f;
#pragma unroll
  for (int q = 0; q < 12; ++q) acc += dot4(w4[sub + q * 16], c4[sub + q * 16]);
  acc = qred16(acc);
  if (sub == 0) act[r] = fmaxf(acc + o1b[r], 0.f);
}

// K5: vocab GEMV, 8 rows/wave/iter (16 NT loads in flight), sum-exp partials
__global__ __launch_bounds__(256) void k_vocab(const float* __restrict__ o2W,
                                               const float* __restrict__ o2b,
                                               const float* __restrict__ act,
                                               float* __restrict__ logits,
                                               float* __restrict__ bsum) {
  __shared__ float swsum[4];
  const int t = threadIdx.x;
  const int lane = t & 63, sub = lane & 15, grp = lane >> 4, w = t >> 6;
  const int gw = blockIdx.x * 4 + w;
  const int nW = 1024 * 4;
  const f4v* a4 = (const f4v*)act;
  f4v ar[8];
#pragma unroll
  for (int q = 0; q < 8; ++q) ar[q] = a4[sub + q * 16];
  float sumexp = 0.f;
  for (int v0 = gw * 8; v0 < V_; v0 += nW * 8) {
    const int vA = v0 + grp;
    const int vB = v0 + 4 + grp;
    float accA = 0.f, accB = 0.f;
    if (vB < V_) {
      const f4v* wa = (const f4v*)(o2W + (size_t)vA * H_);
      const f4v* wb = (const f4v*)(o2W + (size_t)vB * H_);
      f4v la[8], lb[8];
#pragma unroll
      for (int q = 0; q < 8; ++q) la[q] = __builtin_nontemporal_load(&wa[sub + q * 16]);
#pragma unroll
      for (int q = 0; q < 8; ++q) lb[q] = __builtin_nontemporal_load(&wb[sub + q * 16]);
#pragma unroll
      for (int q = 0; q < 8; ++q) { accA += dot4v(la[q], ar[q]); accB += dot4v(lb[q], ar[q]); }
    } else if (vA < V_) {
      const f4v* wa = (const f4v*)(o2W + (size_t)vA * H_);
      f4v la[8];
#pragma unroll
      for (int q = 0; q < 8; ++q) la[q] = __builtin_nontemporal_load(&wa[sub + q * 16]);
#pragma unroll
      for (int q = 0; q < 8; ++q) accA += dot4v(la[q], ar[q]);
    }
    accA = qred16(accA);
    accB = qred16(accB);
    if (sub == 0) {
      if (vA < V_) { float lg = accA + o2b[vA]; logits[vA] = lg; sumexp += __expf(lg); }
      if (vB < V_) { float lg = accB + o2b[vB]; logits[vB] = lg; sumexp += __expf(lg); }
    }
  }
  sumexp = wred64(sumexp);
  if (lane == 0) swsum[w] = sumexp;
  __syncthreads();
  if (t == 0) bsum[blockIdx.x] = swsum[0] + swsum[1] + swsum[2] + swsum[3];
}

// K6: redundant logZ reduce per block + y = logits - logZ
__global__ __launch_bounds__(256) void k_final(const float* __restrict__ logits,
                                               const float* __restrict__ bsum,
                                               float* __restrict__ y) {
  __shared__ float sr[256];
  const int t = threadIdx.x;
  float s = bsum[t] + bsum[t + 256] + bsum[t + 512] + bsum[t + 768];
  sr[t] = s; __syncthreads();
  for (int o = 128; o; o >>= 1) { if (t < o) sr[t] += sr[t + o]; __syncthreads(); }
  const float lz = logf(sr[0]);
  const int i = blockIdx.x * 256 + t;
  float4 l = ((const float4*)logits)[i];
  ((float4*)y)[i] = make_float4(l.x - lz, l.y - lz, l.z - lz, l.w - lz);
}

extern "C" void kernel_launch(void* const* d_in, const int* in_sizes, int n_in,
                              void* d_out, int out_size, void* d_ws, size_t ws_size,
                              hipStream_t stream) {
  const int*   ctx  = (const int*)d_in[0];
  const float* wemb = (const float*)d_in[1];
  const float* a1W  = (const float*)d_in[2];
  const float* a1b  = (const float*)d_in[3];
  const float* a2W  = (const float*)d_in[4];
  const float* a2b  = (const float*)d_in[5];
  const float* Wih  = (const float*)d_in[6];
  const float* Whh  = (const float*)d_in[7];
  const float* bih  = (const float*)d_in[8];
  const float* bhh  = (const float*)d_in[9];
  const float* o1W  = (const float*)d_in[10];
  const float* o1b  = (const float*)d_in[11];
  const float* o2W  = (const float*)d_in[12];
  const float* o2b  = (const float*)d_in[13];
  const float* h0   = (const float*)d_in[14];
  const int*   nfp  = (const int*)d_in[15];
  float* ws = (float*)d_ws;
  float* y  = (float*)d_out;
  int* cnt = (int*)(ws + WS_CNT);

  hipMemsetAsync(cnt, 0, 3 * sizeof(int), stream);
  k_encode<<<266, 256, 0, stream>>>(ctx, wemb, ws + WS_FE, a1W, a1b, h0,
                                    ws + WS_EBIAS, nfp, ws + WS_MEANP, cnt);
  k_energy<<<125, 256, 0, stream>>>(ws + WS_FE, a1W, ws + WS_EBIAS, a2W, a2b, nfp,
                                    ws + WS_ENERGY, ws + WS_AW, ws + WS_FMAX,
                                    y + V_, cnt);
  k_gates_gru<<<136, 256, 0, stream>>>(Wih, bih, Whh, bhh, wemb, ws + WS_FMAX, h0,
                                       ws + WS_AW, ws + WS_FE, ws + WS_AWFP,
                                       ws + WS_HNEW, y + V_ + MCL_);
  k_out1<<<32, 256, 0, stream>>>(o1W, o1b, ws + WS_HNEW, ws + WS_AWFP, ws + WS_ACT);
  k_vocab<<<1024, 256, 0, stream>>>(o2W, o2b, ws + WS_ACT, ws + WS_LOGITS, ws + WS_BSUM);
  k_final<<<V_ / 1024, 256, 0, stream>>>(ws + WS_LOGITS, ws + WS_BSUM, y);
}

// Round 6
// 125.334 us; speedup vs baseline: 1.1542x; 1.1542x over previous
//
#include <hip/hip_runtime.h>
#include <math.h>

#define E_    256
#define H_    512
#define F_    100
#define MCL_  500
#define CTX_  499
#define V_    128000
#define EPS_  1e-8f

typedef float f4v __attribute__((ext_vector_type(4)));

// workspace layout (float offsets)
#define WS_FE      0                      // 500*256 (row 499 = mean fact)
#define WS_ENERGY  (WS_FE + MCL_*E_)      // 500
#define WS_EBIAS   (WS_ENERGY + MCL_)     // 500
#define WS_AW      (WS_EBIAS + MCL_)      // 512 (500 used)
#define WS_AWFP    (WS_AW + 512)          // 8*256 awf partials
#define WS_FMAX    (WS_AWFP + 8*E_)       // 256
#define WS_HNEW    (WS_FMAX + E_)         // 512
#define WS_ACT     (WS_HNEW + H_)         // 512
#define WS_LOGITS  (WS_ACT + H_)          // 128000
#define WS_BSUM    (WS_LOGITS + V_)       // 1024
#define WS_CNT     (WS_BSUM + 1024)       // 1 int (energy ticket)

__device__ __forceinline__ float wred64(float v) {
#pragma unroll
  for (int o = 32; o; o >>= 1) v += __shfl_xor(v, o, 64);
  return v;
}
__device__ __forceinline__ float qred16(float v) {
#pragma unroll
  for (int o = 8; o; o >>= 1) v += __shfl_xor(v, o, 64);
  return v;
}
__device__ __forceinline__ float dot4(float4 a, float4 b) {
  return a.x*b.x + a.y*b.y + a.z*b.z + a.w*b.w;
}
__device__ __forceinline__ float dot4v(f4v a, f4v b) {
  return a.x*b.x + a.y*b.y + a.z*b.z + a.w*b.w;
}

// K1: blocks 0-249: facts (2 rows/block, float2); blocks 250-257: ebias; b0 zeroes cnt
__global__ __launch_bounds__(256) void k_encode(const int* __restrict__ ctx,
                                                const float* __restrict__ wemb,
                                                float* __restrict__ fe,
                                                const float* __restrict__ a1W,
                                                const float* __restrict__ a1b,
                                                const float* __restrict__ h0,
                                                float* __restrict__ ebias,
                                                int* __restrict__ cnt) {
  __shared__ int toks[2][F_];
  const int t = threadIdx.x;
  if (blockIdx.x >= 250) {  // ebias: ebias[j] = a1b[j] + h0 . a1W[j,256:768]
    const int lane = t & 63, sub = lane & 15, grp = lane >> 4;
    const int wid = (blockIdx.x - 250) * 4 + (t >> 6);
    const float4* h4 = (const float4*)h0;
    float4 hr[8];
#pragma unroll
    for (int q = 0; q < 8; ++q) hr[q] = h4[sub + q * 16];
    for (int j0 = wid * 4; j0 < MCL_; j0 += 32 * 4) {
      const int j = j0 + grp;
      if (j < MCL_) {
        const float4* w4 = (const float4*)(a1W + (size_t)j * (E_ + H_) + E_);
        float acc = 0.f;
#pragma unroll
        for (int q = 0; q < 8; ++q) acc += dot4(w4[sub + q * 16], hr[q]);
        acc = qred16(acc);
        if (sub == 0) ebias[j] = acc + a1b[j];
      }
    }
    return;
  }
  if (blockIdx.x == 0 && t == 0) *cnt = 0;
  const int i0 = blockIdx.x * 2;
  const int i1 = i0 + 1;
  if (t < F_) toks[0][t] = ctx[i0 * F_ + t];
  else if (t < 2 * F_) toks[1][t - F_] = (i1 < CTX_) ? ctx[i1 * F_ + (t - F_)] : 0;
  __syncthreads();
  const int row = t >> 7, tt = t & 127;
  const int i = i0 + row;
  const float e0n = (2 * tt) * (1.0f / 255.0f);
  const float e1n = (2 * tt + 1) * (1.0f / 255.0f);
  float x0 = 0.f, y0 = 0.f, x1 = 0.f, y1 = 0.f, x2 = 0.f, y2 = 0.f, x3 = 0.f, y3 = 0.f;
#pragma unroll 5
  for (int f = 0; f < F_; f += 4) {
#pragma unroll
    for (int u = 0; u < 4; ++u) {
      float s = (f + u) * (1.0f / 99.0f);
      float A = 1.0f - s, B = 1.0f - 2.0f * s;
      float2 v = ((const float2*)(wemb + (size_t)toks[row][f + u] * E_))[tt];
      if (u == 0)      { x0 = fmaf(v.x, A - e0n * B, x0); y0 = fmaf(v.y, A - e1n * B, y0); }
      else if (u == 1) { x1 = fmaf(v.x, A - e0n * B, x1); y1 = fmaf(v.y, A - e1n * B, y1); }
      else if (u == 2) { x2 = fmaf(v.x, A - e0n * B, x2); y2 = fmaf(v.y, A - e1n * B, y2); }
      else             { x3 = fmaf(v.x, A - e0n * B, x3); y3 = fmaf(v.y, A - e1n * B, y3); }
    }
  }
  if (i < CTX_) {
    float2 r; r.x = (x0 + x1) + (x2 + x3); r.y = (y0 + y1) + (y2 + y3);
    ((float2*)(fe + (size_t)i * E_))[tt] = r;
  }
}

// K2: energy GEMV (block 124 also computes mean row, overlapped by other 124 blocks);
//     last-ticket block: softmax + log_aw + argmax + aw_ws + fmaxrow (NO awf loop)
__global__ __launch_bounds__(256) void k_energy(float* __restrict__ fe,
                                                const float* __restrict__ a1W,
                                                const float* __restrict__ ebias,
                                                const float* __restrict__ a2W,
                                                const float* __restrict__ a2b,
                                                const int* __restrict__ nfp,
                                                float* __restrict__ energy,
                                                float* __restrict__ aw_ws,
                                                float* __restrict__ fmaxrow,
                                                float* __restrict__ out_logaw,
                                                int* __restrict__ cnt) {
  __shared__ float sfe[4][E_];
  __shared__ float sred[4][256];
  __shared__ int sticket;
  const int t = threadIdx.x;
  const int i0 = blockIdx.x * 4;
  const int nf = *nfp;

  if (blockIdx.x == 124) {
    float s0 = 0.f, s1 = 0.f, s2 = 0.f, s3 = 0.f;
    int i = 0;
    for (; i + 4 <= nf; i += 4) {
      s0 += fe[(i + 0) * E_ + t]; s1 += fe[(i + 1) * E_ + t];
      s2 += fe[(i + 2) * E_ + t]; s3 += fe[(i + 3) * E_ + t];
    }
    for (; i < nf; ++i) s0 += fe[i * E_ + t];
    float mv = ((s0 + s1) + (s2 + s3)) / (float)nf;
    sfe[3][t] = mv;
    fe[CTX_ * E_ + t] = mv;
    sfe[0][t] = fe[496 * E_ + t];
    sfe[1][t] = fe[497 * E_ + t];
    sfe[2][t] = fe[498 * E_ + t];
  } else {
#pragma unroll
    for (int r = 0; r < 4; ++r) sfe[r][t] = fe[(i0 + r) * E_ + t];
  }
  __syncthreads();
  float c0 = 0.f, c1 = 0.f, c2 = 0.f, c3 = 0.f;
  const float4* s0p = (const float4*)sfe[0];
  const float4* s1p = (const float4*)sfe[1];
  const float4* s2p = (const float4*)sfe[2];
  const float4* s3p = (const float4*)sfe[3];
  for (int j = t; j < MCL_; j += 256) {
    const float4* w4 = (const float4*)(a1W + (size_t)j * (E_ + H_));
    float d0 = 0.f, d1 = 0.f, d2 = 0.f, d3 = 0.f;
#pragma unroll 8
    for (int q = 0; q < E_ / 4; ++q) {
      float4 a = w4[q];
      d0 += dot4(a, s0p[q]);
      d1 += dot4(a, s1p[q]);
      d2 += dot4(a, s2p[q]);
      d3 += dot4(a, s3p[q]);
    }
    float bj = ebias[j], wj = a2W[j];
    c0 = fmaf(wj, tanhf(d0 + bj), c0);
    c1 = fmaf(wj, tanhf(d1 + bj), c1);
    c2 = fmaf(wj, tanhf(d2 + bj), c2);
    c3 = fmaf(wj, tanhf(d3 + bj), c3);
  }
  sred[0][t] = c0; sred[1][t] = c1; sred[2][t] = c2; sred[3][t] = c3;
  __syncthreads();
  for (int s = 128; s; s >>= 1) {
    if (t < s) {
#pragma unroll
      for (int r = 0; r < 4; ++r) sred[r][t] += sred[r][t + s];
    }
    __syncthreads();
  }
  if (t < 4) energy[i0 + t] = sred[t][0] + a2b[0];

  __threadfence();
  if (t == 0) sticket = atomicAdd(cnt, 1);
  __syncthreads();
  if (sticket != 124) return;
  __threadfence();

  // ---- cheap softmax tail: 500 elems + 1KB fmaxrow copy ----
  float* red = sred[0];
  int* idx = (int*)sred[1];
  float ev0 = energy[t];
  float ev1 = (t + 256 < MCL_) ? energy[t + 256] : -1e30f;
  red[t] = fmaxf(ev0, ev1); __syncthreads();
  for (int s = 128; s; s >>= 1) { if (t < s) red[t] = fmaxf(red[t], red[t + s]); __syncthreads(); }
  const float mx = red[0]; __syncthreads();

  float p0 = __expf(ev0 - mx);
  float p1 = (t + 256 < MCL_) ? __expf(ev1 - mx) : 0.f;
  red[t] = p0 + p1; __syncthreads();
  for (int s = 128; s; s >>= 1) { if (t < s) red[t] += red[t + s]; __syncthreads(); }
  const float S1 = red[0]; __syncthreads();

  float m0 = ((t < nf) || (t == MCL_ - 1)) ? 1.f : 0.f;
  float m1 = (((t + 256) < nf) || ((t + 256) == MCL_ - 1)) ? 1.f : 0.f;
  float a0 = p0 / S1 * m0 + EPS_;
  float a1 = (t + 256 < MCL_) ? (p1 / S1 * m1 + EPS_) : 0.f;
  red[t] = a0 + a1; __syncthreads();
  for (int s = 128; s; s >>= 1) { if (t < s) red[t] += red[t + s]; __syncthreads(); }
  const float S2 = red[0]; __syncthreads();

  a0 /= S2; a1 /= S2;
  out_logaw[t] = logf(a0);
  aw_ws[t] = a0;
  if (t + 256 < MCL_) { out_logaw[t + 256] = logf(a1); aw_ws[t + 256] = a1; }

  float bv; int bi;
  if ((t + 256 < MCL_) && (a1 > a0)) { bv = a1; bi = t + 256; } else { bv = a0; bi = t; }
  red[t] = bv; idx[t] = bi; __syncthreads();
  for (int s = 128; s; s >>= 1) {
    if (t < s) {
      float o = red[t + s]; int oi = idx[t + s];
      if (o > red[t] || (o == red[t] && oi < idx[t])) { red[t] = o; idx[t] = oi; }
    }
    __syncthreads();
  }
  const int fidx = idx[0]; __syncthreads();
  fmaxrow[t] = fe[fidx * E_ + t];
}

// K3: blocks 0-127 gates+GRU (one h per wave); blocks 128-135 awf partials (no atomics)
__global__ __launch_bounds__(256) void k_gates_gru(const float* __restrict__ Wih,
                                                   const float* __restrict__ bih,
                                                   const float* __restrict__ Whh,
                                                   const float* __restrict__ bhh,
                                                   const float* __restrict__ wemb,
                                                   const float* __restrict__ fmaxrow,
                                                   const float* __restrict__ h0,
                                                   const float* __restrict__ aw,
                                                   const float* __restrict__ fe,
                                                   float* __restrict__ awfp,
                                                   float* __restrict__ hnew,
                                                   float* __restrict__ out_hidden) {
  const int t = threadIdx.x;
  const int b = blockIdx.x;
  if (b >= 128) {  // awfp[m][e] = sum_{i in chunk} aw[i]*fe[i,e]
    const int m = b - 128;
    const int lo = m * 63;
    const int hi = min(MCL_, lo + 63);
    float pa = 0.f, pb = 0.f;
    int i = lo;
    for (; i + 2 <= hi; i += 2) {
      pa = fmaf(aw[i], fe[i * E_ + t], pa);
      pb = fmaf(aw[i + 1], fe[(i + 1) * E_ + t], pb);
    }
    if (i < hi) pa = fmaf(aw[i], fe[i * E_ + t], pa);
    awfp[m * E_ + t] = pa + pb;
    return;
  }
  const int lane = t & 63, w = t >> 6;
  const int h = b * 4 + w;
  const float4* xa4 = (const float4*)(wemb + E_);  // word_emb row 1
  const float4* xb4 = (const float4*)fmaxrow;
  const float4* h4  = (const float4*)h0;
  float4 xav = xa4[lane], xbv = xb4[lane];
  float4 hva = h4[lane], hvb = h4[lane + 64];
  const float* rr = Wih + (size_t)h * (2 * E_ + F_);
  const float* rz = Wih + (size_t)(H_ + h) * (2 * E_ + F_);
  const float* rn = Wih + (size_t)(2 * H_ + h) * (2 * E_ + F_);
  float gir = dot4(((const float4*)rr)[lane], xav) + dot4(((const float4*)(rr + E_ + F_))[lane], xbv);
  float giz = dot4(((const float4*)rz)[lane], xav) + dot4(((const float4*)(rz + E_ + F_))[lane], xbv);
  float gin = dot4(((const float4*)rn)[lane], xav) + dot4(((const float4*)(rn + E_ + F_))[lane], xbv);
  const float4* wr = (const float4*)(Whh + (size_t)h * H_);
  const float4* wz = (const float4*)(Whh + (size_t)(H_ + h) * H_);
  const float4* wn = (const float4*)(Whh + (size_t)(2 * H_ + h) * H_);
  float ghr = dot4(wr[lane], hva) + dot4(wr[lane + 64], hvb);
  float ghz = dot4(wz[lane], hva) + dot4(wz[lane + 64], hvb);
  float ghn = dot4(wn[lane], hva) + dot4(wn[lane + 64], hvb);
  gir = wred64(gir); giz = wred64(giz); gin = wred64(gin);
  ghr = wred64(ghr); ghz = wred64(ghz); ghn = wred64(ghn);
  if (lane == 0) {
    float r = 1.f / (1.f + __expf(-(gir + bih[h] + ghr + bhh[h])));
    float z = 1.f / (1.f + __expf(-(giz + bih[H_ + h] + ghz + bhh[H_ + h])));
    float n = tanhf(gin + bih[2 * H_ + h] + r * (ghn + bhh[2 * H_ + h]));
    float hv = (1.f - z) * n + z * h0[h];
    hnew[h] = hv;
    out_hidden[h] = hv;
  }
}

// K4: act = relu([h_new | sum(awfp)] . out1_W^T + out1_b)
__global__ __launch_bounds__(256) void k_out1(const float* __restrict__ o1W,
                                              const float* __restrict__ o1b,
                                              const float* __restrict__ hnew,
                                              const float* __restrict__ awfp,
                                              float* __restrict__ act) {
  __shared__ float cat[H_ + E_];
  const int t = threadIdx.x;
#pragma unroll
  for (int idx = t; idx < H_; idx += 256) cat[idx] = hnew[idx];
  {
    float s = 0.f;
#pragma unroll
    for (int q = 0; q < 8; ++q) s += awfp[q * E_ + t];
    cat[H_ + t] = s;
  }
  __syncthreads();
  const int lane = t & 63, sub = lane & 15, grp = lane >> 4;
  const int gw = blockIdx.x * 4 + (t >> 6);
  const float4* c4 = (const float4*)cat;
  const int r = gw * 4 + grp;
  const float4* w4 = (const float4*)(o1W + (size_t)r * (H_ + E_));
  float acc = 0.f;
#pragma unroll
  for (int q = 0; q < 12; ++q) acc += dot4(w4[sub + q * 16], c4[sub + q * 16]);
  acc = qred16(acc);
  if (sub == 0) act[r] = fmaxf(acc + o1b[r], 0.f);
}

// K5: vocab GEMV, 8 rows/wave/iter (16 NT loads in flight), sum-exp partials
__global__ __launch_bounds__(256) void k_vocab(const float* __restrict__ o2W,
                                               const float* __restrict__ o2b,
                                               const float* __restrict__ act,
                                               float* __restrict__ logits,
                                               float* __restrict__ bsum) {
  __shared__ float swsum[4];
  const int t = threadIdx.x;
  const int lane = t & 63, sub = lane & 15, grp = lane >> 4, w = t >> 6;
  const int gw = blockIdx.x * 4 + w;
  const int nW = 1024 * 4;
  const f4v* a4 = (const f4v*)act;
  f4v ar[8];
#pragma unroll
  for (int q = 0; q < 8; ++q) ar[q] = a4[sub + q * 16];
  float sumexp = 0.f;
  for (int v0 = gw * 8; v0 < V_; v0 += nW * 8) {
    const int vA = v0 + grp;
    const int vB = v0 + 4 + grp;
    float accA = 0.f, accB = 0.f;
    if (vB < V_) {
      const f4v* wa = (const f4v*)(o2W + (size_t)vA * H_);
      const f4v* wb = (const f4v*)(o2W + (size_t)vB * H_);
      f4v la[8], lb[8];
#pragma unroll
      for (int q = 0; q < 8; ++q) la[q] = __builtin_nontemporal_load(&wa[sub + q * 16]);
#pragma unroll
      for (int q = 0; q < 8; ++q) lb[q] = __builtin_nontemporal_load(&wb[sub + q * 16]);
#pragma unroll
      for (int q = 0; q < 8; ++q) { accA += dot4v(la[q], ar[q]); accB += dot4v(lb[q], ar[q]); }
    } else if (vA < V_) {
      const f4v* wa = (const f4v*)(o2W + (size_t)vA * H_);
      f4v la[8];
#pragma unroll
      for (int q = 0; q < 8; ++q) la[q] = __builtin_nontemporal_load(&wa[sub + q * 16]);
#pragma unroll
      for (int q = 0; q < 8; ++q) accA += dot4v(la[q], ar[q]);
    }
    accA = qred16(accA);
    accB = qred16(accB);
    if (sub == 0) {
      if (vA < V_) { float lg = accA + o2b[vA]; logits[vA] = lg; sumexp += __expf(lg); }
      if (vB < V_) { float lg = accB + o2b[vB]; logits[vB] = lg; sumexp += __expf(lg); }
    }
  }
  sumexp = wred64(sumexp);
  if (lane == 0) swsum[w] = sumexp;
  __syncthreads();
  if (t == 0) bsum[blockIdx.x] = swsum[0] + swsum[1] + swsum[2] + swsum[3];
}

// K6: redundant logZ reduce per block + y = logits - logZ
__global__ __launch_bounds__(256) void k_final(const float* __restrict__ logits,
                                               const float* __restrict__ bsum,
                                               float* __restrict__ y) {
  __shared__ float sr[256];
  const int t = threadIdx.x;
  float s = bsum[t] + bsum[t + 256] + bsum[t + 512] + bsum[t + 768];
  sr[t] = s; __syncthreads();
  for (int o = 128; o; o >>= 1) { if (t < o) sr[t] += sr[t + o]; __syncthreads(); }
  const float lz = logf(sr[0]);
  const int i = blockIdx.x * 256 + t;
  float4 l = ((const float4*)logits)[i];
  ((float4*)y)[i] = make_float4(l.x - lz, l.y - lz, l.z - lz, l.w - lz);
}

extern "C" void kernel_launch(void* const* d_in, const int* in_sizes, int n_in,
                              void* d_out, int out_size, void* d_ws, size_t ws_size,
                              hipStream_t stream) {
  const int*   ctx  = (const int*)d_in[0];
  const float* wemb = (const float*)d_in[1];
  const float* a1W  = (const float*)d_in[2];
  const float* a1b  = (const float*)d_in[3];
  const float* a2W  = (const float*)d_in[4];
  const float* a2b  = (const float*)d_in[5];
  const float* Wih  = (const float*)d_in[6];
  const float* Whh  = (const float*)d_in[7];
  const float* bih  = (const float*)d_in[8];
  const float* bhh  = (const float*)d_in[9];
  const float* o1W  = (const float*)d_in[10];
  const float* o1b  = (const float*)d_in[11];
  const float* o2W  = (const float*)d_in[12];
  const float* o2b  = (const float*)d_in[13];
  const float* h0   = (const float*)d_in[14];
  const int*   nfp  = (const int*)d_in[15];
  float* ws = (float*)d_ws;
  float* y  = (float*)d_out;
  int* cnt = (int*)(ws + WS_CNT);

  k_encode<<<258, 256, 0, stream>>>(ctx, wemb, ws + WS_FE, a1W, a1b, h0,
                                    ws + WS_EBIAS, cnt);
  k_energy<<<125, 256, 0, stream>>>(ws + WS_FE, a1W, ws + WS_EBIAS, a2W, a2b, nfp,
                                    ws + WS_ENERGY, ws + WS_AW, ws + WS_FMAX,
                                    y + V_, cnt);
  k_gates_gru<<<136, 256, 0, stream>>>(Wih, bih, Whh, bhh, wemb, ws + WS_FMAX, h0,
                                       ws + WS_AW, ws + WS_FE, ws + WS_AWFP,
                                       ws + WS_HNEW, y + V_ + MCL_);
  k_out1<<<32, 256, 0, stream>>>(o1W, o1b, ws + WS_HNEW, ws + WS_AWFP, ws + WS_ACT);
  k_vocab<<<1024, 256, 0, stream>>>(o2W, o2b, ws + WS_ACT, ws + WS_LOGITS, ws + WS_BSUM);
  k_final<<<V_ / 1024, 256, 0, stream>>>(ws + WS_LOGITS, ws + WS_BSUM, y);
}

// Round 7
// 120.201 us; speedup vs baseline: 1.2035x; 1.0427x over previous
//
#include <hip/hip_runtime.h>
#include <math.h>

#define E_    256
#define H_    512
#define F_    100
#define MCL_  500
#define CTX_  499
#define V_    128000
#define EPS_  1e-8f

typedef float f4v __attribute__((ext_vector_type(4)));

// workspace layout (float offsets)
#define WS_FE      0                      // 500*256 (row 499 = mean fact)
#define WS_ENERGY  (WS_FE + MCL_*E_)      // 500
#define WS_EBIAS   (WS_ENERGY + MCL_)     // 500
#define WS_AW      (WS_EBIAS + MCL_)      // 512 (500 used)
#define WS_AWFP    (WS_AW + 512)          // 8*256 awf partials
#define WS_FMAX    (WS_AWFP + 8*E_)       // 256
#define WS_HNEW    (WS_FMAX + E_)         // 512
#define WS_ACT     (WS_HNEW + H_)         // 512
#define WS_LOGITS  (WS_ACT + H_)          // 128000
#define WS_BSUM    (WS_LOGITS + V_)       // 1024
#define WS_CNT     (WS_BSUM + 1024)       // 1 int (energy ticket)

__device__ __forceinline__ float wred64(float v) {
#pragma unroll
  for (int o = 32; o; o >>= 1) v += __shfl_xor(v, o, 64);
  return v;
}
__device__ __forceinline__ float qred16(float v) {
#pragma unroll
  for (int o = 8; o; o >>= 1) v += __shfl_xor(v, o, 64);
  return v;
}
__device__ __forceinline__ float dot4(float4 a, float4 b) {
  return a.x*b.x + a.y*b.y + a.z*b.z + a.w*b.w;
}
__device__ __forceinline__ float dot4v(f4v a, f4v b) {
  return a.x*b.x + a.y*b.y + a.z*b.z + a.w*b.w;
}

// K1: blocks 0-249: facts (2 rows/block, float2, 10-deep load batching);
//     blocks 250-257: ebias; b0 zeroes cnt
__global__ __launch_bounds__(256) void k_encode(const int* __restrict__ ctx,
                                                const float* __restrict__ wemb,
                                                float* __restrict__ fe,
                                                const float* __restrict__ a1W,
                                                const float* __restrict__ a1b,
                                                const float* __restrict__ h0,
                                                float* __restrict__ ebias,
                                                int* __restrict__ cnt) {
  __shared__ int toks[2][F_];
  const int t = threadIdx.x;
  if (blockIdx.x >= 250) {  // ebias: ebias[j] = a1b[j] + h0 . a1W[j,256:768]
    const int lane = t & 63, sub = lane & 15, grp = lane >> 4;
    const int wid = (blockIdx.x - 250) * 4 + (t >> 6);
    const float4* h4 = (const float4*)h0;
    float4 hr[8];
#pragma unroll
    for (int q = 0; q < 8; ++q) hr[q] = h4[sub + q * 16];
    for (int j0 = wid * 4; j0 < MCL_; j0 += 32 * 4) {
      const int j = j0 + grp;
      if (j < MCL_) {
        const float4* w4 = (const float4*)(a1W + (size_t)j * (E_ + H_) + E_);
        float acc = 0.f;
#pragma unroll
        for (int q = 0; q < 8; ++q) acc += dot4(w4[sub + q * 16], hr[q]);
        acc = qred16(acc);
        if (sub == 0) ebias[j] = acc + a1b[j];
      }
    }
    return;
  }
  if (blockIdx.x == 0 && t == 0) *cnt = 0;
  const int i0 = blockIdx.x * 2;
  const int i1 = i0 + 1;
  if (t < F_) toks[0][t] = ctx[i0 * F_ + t];
  else if (t < 2 * F_) toks[1][t - F_] = (i1 < CTX_) ? ctx[i1 * F_ + (t - F_)] : 0;
  __syncthreads();
  const int row = t >> 7, tt = t & 127;
  const int i = i0 + row;
  const float e0n = (2 * tt) * (1.0f / 255.0f);
  const float e1n = (2 * tt + 1) * (1.0f / 255.0f);
  float ax = 0.f, ay = 0.f, bx = 0.f, by = 0.f;
  // 10-deep explicit load batching: keep ~10 gathers in flight per lane
#pragma unroll
  for (int f0 = 0; f0 < F_; f0 += 10) {
    float2 vb[10];
#pragma unroll
    for (int u = 0; u < 10; ++u)
      vb[u] = ((const float2*)(wemb + (size_t)toks[row][f0 + u] * E_))[tt];
#pragma unroll
    for (int u = 0; u < 10; ++u) {
      float s = (f0 + u) * (1.0f / 99.0f);
      float A = 1.0f - s, B = 1.0f - 2.0f * s;
      if (u & 1) { bx = fmaf(vb[u].x, A - e0n * B, bx); by = fmaf(vb[u].y, A - e1n * B, by); }
      else       { ax = fmaf(vb[u].x, A - e0n * B, ax); ay = fmaf(vb[u].y, A - e1n * B, ay); }
    }
  }
  if (i < CTX_) {
    float2 r; r.x = ax + bx; r.y = ay + by;
    ((float2*)(fe + (size_t)i * E_))[tt] = r;
  }
}

// K2: energy GEMV (block 124 also computes mean row, 8-deep ILP);
//     last-ticket block: softmax + log_aw + argmax + aw_ws + fmaxrow
__global__ __launch_bounds__(256) void k_energy(float* __restrict__ fe,
                                                const float* __restrict__ a1W,
                                                const float* __restrict__ ebias,
                                                const float* __restrict__ a2W,
                                                const float* __restrict__ a2b,
                                                const int* __restrict__ nfp,
                                                float* __restrict__ energy,
                                                float* __restrict__ aw_ws,
                                                float* __restrict__ fmaxrow,
                                                float* __restrict__ out_logaw,
                                                int* __restrict__ cnt) {
  __shared__ float sfe[4][E_];
  __shared__ float sred[4][256];
  __shared__ int sticket;
  const int t = threadIdx.x;
  const int i0 = blockIdx.x * 4;
  const int nf = *nfp;

  if (blockIdx.x == 124) {
    float s0 = 0.f, s1 = 0.f, s2 = 0.f, s3 = 0.f;
    float s4 = 0.f, s5 = 0.f, s6 = 0.f, s7 = 0.f;
    int i = 0;
    for (; i + 8 <= nf; i += 8) {
      s0 += fe[(i + 0) * E_ + t]; s1 += fe[(i + 1) * E_ + t];
      s2 += fe[(i + 2) * E_ + t]; s3 += fe[(i + 3) * E_ + t];
      s4 += fe[(i + 4) * E_ + t]; s5 += fe[(i + 5) * E_ + t];
      s6 += fe[(i + 6) * E_ + t]; s7 += fe[(i + 7) * E_ + t];
    }
    for (; i < nf; ++i) s0 += fe[i * E_ + t];
    float mv = (((s0 + s1) + (s2 + s3)) + ((s4 + s5) + (s6 + s7))) / (float)nf;
    sfe[3][t] = mv;
    fe[CTX_ * E_ + t] = mv;
    sfe[0][t] = fe[496 * E_ + t];
    sfe[1][t] = fe[497 * E_ + t];
    sfe[2][t] = fe[498 * E_ + t];
  } else {
#pragma unroll
    for (int r = 0; r < 4; ++r) sfe[r][t] = fe[(i0 + r) * E_ + t];
  }
  __syncthreads();
  float c0 = 0.f, c1 = 0.f, c2 = 0.f, c3 = 0.f;
  const float4* s0p = (const float4*)sfe[0];
  const float4* s1p = (const float4*)sfe[1];
  const float4* s2p = (const float4*)sfe[2];
  const float4* s3p = (const float4*)sfe[3];
  for (int j = t; j < MCL_; j += 256) {
    const float4* w4 = (const float4*)(a1W + (size_t)j * (E_ + H_));
    float d0 = 0.f, d1 = 0.f, d2 = 0.f, d3 = 0.f;
#pragma unroll 8
    for (int q = 0; q < E_ / 4; ++q) {
      float4 a = w4[q];
      d0 += dot4(a, s0p[q]);
      d1 += dot4(a, s1p[q]);
      d2 += dot4(a, s2p[q]);
      d3 += dot4(a, s3p[q]);
    }
    float bj = ebias[j], wj = a2W[j];
    c0 = fmaf(wj, tanhf(d0 + bj), c0);
    c1 = fmaf(wj, tanhf(d1 + bj), c1);
    c2 = fmaf(wj, tanhf(d2 + bj), c2);
    c3 = fmaf(wj, tanhf(d3 + bj), c3);
  }
  sred[0][t] = c0; sred[1][t] = c1; sred[2][t] = c2; sred[3][t] = c3;
  __syncthreads();
  for (int s = 128; s; s >>= 1) {
    if (t < s) {
#pragma unroll
      for (int r = 0; r < 4; ++r) sred[r][t] += sred[r][t + s];
    }
    __syncthreads();
  }
  if (t < 4) energy[i0 + t] = sred[t][0] + a2b[0];

  __threadfence();
  if (t == 0) sticket = atomicAdd(cnt, 1);
  __syncthreads();
  if (sticket != 124) return;
  __threadfence();

  // ---- cheap softmax tail: 500 elems + 1KB fmaxrow copy ----
  float* red = sred[0];
  int* idx = (int*)sred[1];
  float ev0 = energy[t];
  float ev1 = (t + 256 < MCL_) ? energy[t + 256] : -1e30f;
  red[t] = fmaxf(ev0, ev1); __syncthreads();
  for (int s = 128; s; s >>= 1) { if (t < s) red[t] = fmaxf(red[t], red[t + s]); __syncthreads(); }
  const float mx = red[0]; __syncthreads();

  float p0 = __expf(ev0 - mx);
  float p1 = (t + 256 < MCL_) ? __expf(ev1 - mx) : 0.f;
  red[t] = p0 + p1; __syncthreads();
  for (int s = 128; s; s >>= 1) { if (t < s) red[t] += red[t + s]; __syncthreads(); }
  const float S1 = red[0]; __syncthreads();

  float m0 = ((t < nf) || (t == MCL_ - 1)) ? 1.f : 0.f;
  float m1 = (((t + 256) < nf) || ((t + 256) == MCL_ - 1)) ? 1.f : 0.f;
  float a0 = p0 / S1 * m0 + EPS_;
  float a1 = (t + 256 < MCL_) ? (p1 / S1 * m1 + EPS_) : 0.f;
  red[t] = a0 + a1; __syncthreads();
  for (int s = 128; s; s >>= 1) { if (t < s) red[t] += red[t + s]; __syncthreads(); }
  const float S2 = red[0]; __syncthreads();

  a0 /= S2; a1 /= S2;
  out_logaw[t] = logf(a0);
  aw_ws[t] = a0;
  if (t + 256 < MCL_) { out_logaw[t + 256] = logf(a1); aw_ws[t + 256] = a1; }

  float bv; int bi;
  if ((t + 256 < MCL_) && (a1 > a0)) { bv = a1; bi = t + 256; } else { bv = a0; bi = t; }
  red[t] = bv; idx[t] = bi; __syncthreads();
  for (int s = 128; s; s >>= 1) {
    if (t < s) {
      float o = red[t + s]; int oi = idx[t + s];
      if (o > red[t] || (o == red[t] && oi < idx[t])) { red[t] = o; idx[t] = oi; }
    }
    __syncthreads();
  }
  const int fidx = idx[0]; __syncthreads();
  fmaxrow[t] = fe[fidx * E_ + t];
}

// K3: blocks 0-127 gates+GRU (one h per wave); blocks 128-135 awf partials (no atomics)
__global__ __launch_bounds__(256) void k_gates_gru(const float* __restrict__ Wih,
                                                   const float* __restrict__ bih,
                                                   const float* __restrict__ Whh,
                                                   const float* __restrict__ bhh,
                                                   const float* __restrict__ wemb,
                                                   const float* __restrict__ fmaxrow,
                                                   const float* __restrict__ h0,
                                                   const float* __restrict__ aw,
                                                   const float* __restrict__ fe,
                                                   float* __restrict__ awfp,
                                                   float* __restrict__ hnew,
                                                   float* __restrict__ out_hidden) {
  const int t = threadIdx.x;
  const int b = blockIdx.x;
  if (b >= 128) {  // awfp[m][e] = sum_{i in chunk} aw[i]*fe[i,e]
    const int m = b - 128;
    const int lo = m * 63;
    const int hi = min(MCL_, lo + 63);
    float pa = 0.f, pb = 0.f, pc = 0.f, pd = 0.f;
    int i = lo;
    for (; i + 4 <= hi; i += 4) {
      pa = fmaf(aw[i], fe[i * E_ + t], pa);
      pb = fmaf(aw[i + 1], fe[(i + 1) * E_ + t], pb);
      pc = fmaf(aw[i + 2], fe[(i + 2) * E_ + t], pc);
      pd = fmaf(aw[i + 3], fe[(i + 3) * E_ + t], pd);
    }
    for (; i < hi; ++i) pa = fmaf(aw[i], fe[i * E_ + t], pa);
    awfp[m * E_ + t] = (pa + pb) + (pc + pd);
    return;
  }
  const int lane = t & 63, w = t >> 6;
  const int h = b * 4 + w;
  const float4* xa4 = (const float4*)(wemb + E_);  // word_emb row 1
  const float4* xb4 = (const float4*)fmaxrow;
  const float4* h4  = (const float4*)h0;
  float4 xav = xa4[lane], xbv = xb4[lane];
  float4 hva = h4[lane], hvb = h4[lane + 64];
  const float* rr = Wih + (size_t)h * (2 * E_ + F_);
  const float* rz = Wih + (size_t)(H_ + h) * (2 * E_ + F_);
  const float* rn = Wih + (size_t)(2 * H_ + h) * (2 * E_ + F_);
  float gir = dot4(((const float4*)rr)[lane], xav) + dot4(((const float4*)(rr + E_ + F_))[lane], xbv);
  float giz = dot4(((const float4*)rz)[lane], xav) + dot4(((const float4*)(rz + E_ + F_))[lane], xbv);
  float gin = dot4(((const float4*)rn)[lane], xav) + dot4(((const float4*)(rn + E_ + F_))[lane], xbv);
  const float4* wr = (const float4*)(Whh + (size_t)h * H_);
  const float4* wz = (const float4*)(Whh + (size_t)(H_ + h) * H_);
  const float4* wn = (const float4*)(Whh + (size_t)(2 * H_ + h) * H_);
  float ghr = dot4(wr[lane], hva) + dot4(wr[lane + 64], hvb);
  float ghz = dot4(wz[lane], hva) + dot4(wz[lane + 64], hvb);
  float ghn = dot4(wn[lane], hva) + dot4(wn[lane + 64], hvb);
  gir = wred64(gir); giz = wred64(giz); gin = wred64(gin);
  ghr = wred64(ghr); ghz = wred64(ghz); ghn = wred64(ghn);
  if (lane == 0) {
    float r = 1.f / (1.f + __expf(-(gir + bih[h] + ghr + bhh[h])));
    float z = 1.f / (1.f + __expf(-(giz + bih[H_ + h] + ghz + bhh[H_ + h])));
    float n = tanhf(gin + bih[2 * H_ + h] + r * (ghn + bhh[2 * H_ + h]));
    float hv = (1.f - z) * n + z * h0[h];
    hnew[h] = hv;
    out_hidden[h] = hv;
  }
}

// K4: act = relu([h_new | sum(awfp)] . out1_W^T + out1_b)  — 128 blocks, row/wave
__global__ __launch_bounds__(256) void k_out1(const float* __restrict__ o1W,
                                              const float* __restrict__ o1b,
                                              const float* __restrict__ hnew,
                                              const float* __restrict__ awfp,
                                              float* __restrict__ act) {
  __shared__ float cat[H_ + E_];
  const int t = threadIdx.x;
#pragma unroll
  for (int idx = t; idx < H_; idx += 256) cat[idx] = hnew[idx];
  {
    float s = 0.f;
#pragma unroll
    for (int q = 0; q < 8; ++q) s += awfp[q * E_ + t];
    cat[H_ + t] = s;
  }
  __syncthreads();
  const int lane = t & 63, w = t >> 6;
  const int r = blockIdx.x * 4 + w;
  const float4* c4 = (const float4*)cat;
  const float4* w4 = (const float4*)(o1W + (size_t)r * (H_ + E_));
  float acc = 0.f;
#pragma unroll
  for (int q = 0; q < 3; ++q) acc += dot4(w4[lane + 64 * q], c4[lane + 64 * q]);
  acc = wred64(acc);
  if (lane == 0) act[r] = fmaxf(acc + o1b[r], 0.f);
}

// K5: vocab GEMV, 8 rows/wave/iter (16 NT loads in flight), sum-exp partials
__global__ __launch_bounds__(256) void k_vocab(const float* __restrict__ o2W,
                                               const float* __restrict__ o2b,
                                               const float* __restrict__ act,
                                               float* __restrict__ logits,
                                               float* __restrict__ bsum) {
  __shared__ float swsum[4];
  const int t = threadIdx.x;
  const int lane = t & 63, sub = lane & 15, grp = lane >> 4, w = t >> 6;
  const int gw = blockIdx.x * 4 + w;
  const int nW = 1024 * 4;
  const f4v* a4 = (const f4v*)act;
  f4v ar[8];
#pragma unroll
  for (int q = 0; q < 8; ++q) ar[q] = a4[sub + q * 16];
  float sumexp = 0.f;
  for (int v0 = gw * 8; v0 < V_; v0 += nW * 8) {
    const int vA = v0 + grp;
    const int vB = v0 + 4 + grp;
    float accA = 0.f, accB = 0.f;
    if (vB < V_) {
      const f4v* wa = (const f4v*)(o2W + (size_t)vA * H_);
      const f4v* wb = (const f4v*)(o2W + (size_t)vB * H_);
      f4v la[8], lb[8];
#pragma unroll
      for (int q = 0; q < 8; ++q) la[q] = __builtin_nontemporal_load(&wa[sub + q * 16]);
#pragma unroll
      for (int q = 0; q < 8; ++q) lb[q] = __builtin_nontemporal_load(&wb[sub + q * 16]);
#pragma unroll
      for (int q = 0; q < 8; ++q) { accA += dot4v(la[q], ar[q]); accB += dot4v(lb[q], ar[q]); }
    } else if (vA < V_) {
      const f4v* wa = (const f4v*)(o2W + (size_t)vA * H_);
      f4v la[8];
#pragma unroll
      for (int q = 0; q < 8; ++q) la[q] = __builtin_nontemporal_load(&wa[sub + q * 16]);
#pragma unroll
      for (int q = 0; q < 8; ++q) accA += dot4v(la[q], ar[q]);
    }
    accA = qred16(accA);
    accB = qred16(accB);
    if (sub == 0) {
      if (vA < V_) { float lg = accA + o2b[vA]; logits[vA] = lg; sumexp += __expf(lg); }
      if (vB < V_) { float lg = accB + o2b[vB]; logits[vB] = lg; sumexp += __expf(lg); }
    }
  }
  sumexp = wred64(sumexp);
  if (lane == 0) swsum[w] = sumexp;
  __syncthreads();
  if (t == 0) bsum[blockIdx.x] = swsum[0] + swsum[1] + swsum[2] + swsum[3];
}

// K6: redundant logZ reduce per block + y = logits - logZ
__global__ __launch_bounds__(256) void k_final(const float* __restrict__ logits,
                                               const float* __restrict__ bsum,
                                               float* __restrict__ y) {
  __shared__ float sr[256];
  const int t = threadIdx.x;
  float s = bsum[t] + bsum[t + 256] + bsum[t + 512] + bsum[t + 768];
  sr[t] = s; __syncthreads();
  for (int o = 128; o; o >>= 1) { if (t < o) sr[t] += sr[t + o]; __syncthreads(); }
  const float lz = logf(sr[0]);
  const int i = blockIdx.x * 256 + t;
  float4 l = ((const float4*)logits)[i];
  ((float4*)y)[i] = make_float4(l.x - lz, l.y - lz, l.z - lz, l.w - lz);
}

extern "C" void kernel_launch(void* const* d_in, const int* in_sizes, int n_in,
                              void* d_out, int out_size, void* d_ws, size_t ws_size,
                              hipStream_t stream) {
  const int*   ctx  = (const int*)d_in[0];
  const float* wemb = (const float*)d_in[1];
  const float* a1W  = (const float*)d_in[2];
  const float* a1b  = (const float*)d_in[3];
  const float* a2W  = (const float*)d_in[4];
  const float* a2b  = (const float*)d_in[5];
  const float* Wih  = (const float*)d_in[6];
  const float* Whh  = (const float*)d_in[7];
  const float* bih  = (const float*)d_in[8];
  const float* bhh  = (const float*)d_in[9];
  const float* o1W  = (const float*)d_in[10];
  const float* o1b  = (const float*)d_in[11];
  const float* o2W  = (const float*)d_in[12];
  const float* o2b  = (const float*)d_in[13];
  const float* h0   = (const float*)d_in[14];
  const int*   nfp  = (const int*)d_in[15];
  float* ws = (float*)d_ws;
  float* y  = (float*)d_out;
  int* cnt = (int*)(ws + WS_CNT);

  k_encode<<<258, 256, 0, stream>>>(ctx, wemb, ws + WS_FE, a1W, a1b, h0,
                                    ws + WS_EBIAS, cnt);
  k_energy<<<125, 256, 0, stream>>>(ws + WS_FE, a1W, ws + WS_EBIAS, a2W, a2b, nfp,
                                    ws + WS_ENERGY, ws + WS_AW, ws + WS_FMAX,
                                    y + V_, cnt);
  k_gates_gru<<<136, 256, 0, stream>>>(Wih, bih, Whh, bhh, wemb, ws + WS_FMAX, h0,
                                       ws + WS_AW, ws + WS_FE, ws + WS_AWFP,
                                       ws + WS_HNEW, y + V_ + MCL_);
  k_out1<<<128, 256, 0, stream>>>(o1W, o1b, ws + WS_HNEW, ws + WS_AWFP, ws + WS_ACT);
  k_vocab<<<1024, 256, 0, stream>>>(o2W, o2b, ws + WS_ACT, ws + WS_LOGITS, ws + WS_BSUM);
  k_final<<<V_ / 1024, 256, 0, stream>>>(ws + WS_LOGITS, ws + WS_BSUM, y);
}